// Round 3
// baseline (64.181 us; speedup 1.0000x reference)
//
#include <hip/hip_runtime.h>

#define B_ 512
#define M_ 32
#define D_ 2048

// K1: one 64-lane wave per row. Row sum + first/last element -> sums[row] = {T, first, last, 0}.
// No LDS, no barriers.
__global__ __launch_bounds__(256) void ephaptic_sums(const float* __restrict__ x,
                                                     float4* __restrict__ sums) {
    const int wave = threadIdx.x >> 6;
    const int lane = threadIdx.x & 63;
    const int row = blockIdx.x * 4 + wave;          // b*32 + m

    const float4* r4 = (const float4*)(x + (size_t)row * D_);
    float sum = 0.f, first = 0.f, last = 0.f;
#pragma unroll
    for (int q = 0; q < 8; ++q) {
        float4 v = r4[lane + 64 * q];
        sum += (v.x + v.y) + (v.z + v.w);
        if (q == 0) first = v.x;   // valid in lane 0
        if (q == 7) last = v.w;    // valid in lane 63
    }
#pragma unroll
    for (int off = 32; off > 0; off >>= 1)
        sum += __shfl_xor(sum, off, 64);
    last = __shfl(last, 63, 64);
    if (lane == 0) sums[row] = make_float4(sum, first, last, 0.f);
}

// K2: one block (256 threads) per row. Each wave redundantly computes the row's 3
// coefficients from sums[] (32-lane gather + shuffle reduce — no LDS, no barrier),
// then streams out = x + coef . w.
__global__ __launch_bounds__(256) void ephaptic_out(const float* __restrict__ x,
                                                    const float* __restrict__ w,
                                                    const float4* __restrict__ sums,
                                                    float* __restrict__ out) {
    const int row = blockIdx.x;       // b*32 + i
    const int b = row >> 5;
    const int i = row & 31;
    const int lane = threadIdx.x & 63;
    const int j = lane & 31;

    // coef reduce: lane j holds decay(i,j) * S_k[b,j]
    const float4 s = sums[b * M_ + j];
    const float dij = (j == i) ? 0.f : __expf(-0.5f * fabsf((float)(i - j)));
    float r0 = dij * (s.x - s.z);     // tap k=0: drop last
    float r1 = dij * s.x;             // tap k=1
    float r2 = dij * (s.x - s.y);     // tap k=2: drop first
#pragma unroll
    for (int off = 16; off > 0; off >>= 1) {
        r0 += __shfl_xor(r0, off, 64);
        r1 += __shfl_xor(r1, off, 64);
        r2 += __shfl_xor(r2, off, 64);
    }
    const float sc = 0.1f / (float)D_;
    const float c0 = r0 * sc, c1 = r1 * sc, c2 = r2 * sc;

    // stream: 512 float4 per row, 2 per thread
    const size_t base = (size_t)row * D_;
    const float4* xr = (const float4*)(x + base);
    float4* orow = (float4*)(out + base);
    const float4* wf = (const float4*)w;
#pragma unroll
    for (int h = 0; h < 2; ++h) {
        const int c4 = threadIdx.x + 256 * h;
        const float4 xv = xr[c4];
        const float4 w0 = wf[c4 * 3 + 0];
        const float4 w1 = wf[c4 * 3 + 1];
        const float4 w2 = wf[c4 * 3 + 2];
        float4 o;
        o.x = xv.x + c0 * w0.x + c1 * w0.y + c2 * w0.z;
        o.y = xv.y + c0 * w0.w + c1 * w1.x + c2 * w1.y;
        o.z = xv.z + c0 * w1.z + c1 * w1.w + c2 * w2.x;
        o.w = xv.w + c0 * w2.y + c1 * w2.z + c2 * w2.w;
        orow[c4] = o;
    }
}

extern "C" void kernel_launch(void* const* d_in, const int* in_sizes, int n_in,
                              void* d_out, int out_size, void* d_ws, size_t ws_size,
                              hipStream_t stream) {
    const float* x = (const float*)d_in[0];
    const float* w = (const float*)d_in[1];
    float* out = (float*)d_out;
    float4* sums = (float4*)d_ws;   // B*M float4 = 256 KB

    ephaptic_sums<<<(B_ * M_) / 4, 256, 0, stream>>>(x, sums);
    ephaptic_out<<<B_ * M_, 256, 0, stream>>>(x, w, sums, out);
}

// Round 5
// 55.338 us; speedup vs baseline: 1.1598x; 1.1598x over previous
//
#include <hip/hip_runtime.h>

#define B_ 512
#define M_ 32
#define D_ 2048

// One block per batch. 1024 threads = 32 rows x 32 threads/row.
// launch_bounds(1024, 4): allow up to 128 VGPR so each thread can HOLD its
// 16 float4s of x in registers across the coef barrier (x fetched from HBM
// exactly once, no phase-C re-load). asm pin prevents load sinking.
__global__ __launch_bounds__(1024, 4) void ephaptic_fused(const float* __restrict__ x,
                                                          const float* __restrict__ w,
                                                          float* __restrict__ out) {
    const int b = blockIdx.x;
    const int tid = threadIdx.x;
    const int m = tid >> 5;   // row 0..31
    const int t = tid & 31;   // position group within row

    __shared__ float sT[M_], sF[M_], sL[M_];
    __shared__ float4 sC[M_ + 1];

    const size_t rowbase = ((size_t)b * M_ + m) * (size_t)D_;
    const float4* row = (const float4*)(x + rowbase);

    // Phase A: load row slice into registers, accumulate row sum.
    float4 v[16];
    float sum = 0.f;
#pragma unroll
    for (int q = 0; q < 16; ++q) {
        v[q] = row[t + 32 * q];
        sum += (v[q].x + v[q].y) + (v[q].z + v[q].w);
    }
    // Pin the loaded values in VGPRs: forbid the compiler from sinking the
    // loads into phase C (it did at launch_bounds(1024) -> VGPR_Count 60).
#pragma unroll
    for (int q = 0; q < 16; ++q)
        asm volatile("" : "+v"(v[q].x), "+v"(v[q].y), "+v"(v[q].z), "+v"(v[q].w));

    // butterfly within the 32-lane row group (xor offsets < 32 stay in-half)
#pragma unroll
    for (int off = 16; off > 0; off >>= 1)
        sum += __shfl_xor(sum, off, 64);
    if (t == 0)  { sT[m] = sum; sF[m] = v[0].x; }    // x[b][m][0]
    if (t == 31) { sL[m] = v[15].w; }                // x[b][m][2047]
    __syncthreads();

    // Phase B: 32x32 decay matvec -> per-row coefficients (one wave works).
    if (tid < M_) {
        const int i = tid;
        float r0 = 0.f, r1 = 0.f, r2 = 0.f;
        for (int j = 0; j < M_; ++j) {
            if (j == i) continue;
            const float dij = __expf(-0.5f * fabsf((float)(i - j)));
            const float T = sT[j];
            r0 += dij * (T - sL[j]);   // tap k=0: drop last element
            r1 += dij * T;             // tap k=1
            r2 += dij * (T - sF[j]);   // tap k=2: drop first element
        }
        const float s = 0.1f / (float)D_;
        sC[i] = make_float4(r0 * s, r1 * s, r2 * s, 0.f);
    }
    __syncthreads();

    // Phase C: out = x + coef . w[c,:]  (w is [D,3] row-major; 12 floats = 3 float4 per c4)
    const float4 co = sC[m];  // LDS broadcast within row group
    const float4* wf = (const float4*)w;
    float4* orow = (float4*)(out + rowbase);
#pragma unroll
    for (int q = 0; q < 16; ++q) {
        const int c4 = t + 32 * q;
        const float4 w0 = wf[c4 * 3 + 0];
        const float4 w1 = wf[c4 * 3 + 1];
        const float4 w2 = wf[c4 * 3 + 2];
        float4 o;
        o.x = v[q].x + co.x * w0.x + co.y * w0.y + co.z * w0.z;
        o.y = v[q].y + co.x * w0.w + co.y * w1.x + co.z * w1.y;
        o.z = v[q].z + co.x * w1.z + co.y * w1.w + co.z * w2.x;
        o.w = v[q].w + co.x * w2.y + co.y * w2.z + co.z * w2.w;
        orow[c4] = o;
    }
}

extern "C" void kernel_launch(void* const* d_in, const int* in_sizes, int n_in,
                              void* d_out, int out_size, void* d_ws, size_t ws_size,
                              hipStream_t stream) {
    const float* x = (const float*)d_in[0];
    const float* w = (const float*)d_in[1];
    float* out = (float*)d_out;
    ephaptic_fused<<<B_, 1024, 0, stream>>>(x, w, out);
}